// Round 11
// baseline (130.136 us; speedup 1.0000x reference)
//
#include <hip/hip_runtime.h>

// GraphPairClassifier v11: megakernel, fp16, 32x32x16 MFMA (half the issue
//   stream of v10's 16x16x32: 2x MACs/instruction, half the A LDS reads).
//   Structure: mean(4) -> L1(3->256) -> L2 -> L3 -> concat(free, r=2g+side)
//   -> H1..H4. Activations LDS-resident; weights in MFMA-fragment order
//   streamed from L2 with register ping-pong prefetch. 32 pairs/block.
//   H4 (N=64) keeps the 16x16 path.
// Dtypes: device inputs FP32 (bf16-quantized values => fp16 conversion of
//   weights exact); output FP32. absmax ~3.9e-3 stable since R6.

typedef _Float16 half8 __attribute__((ext_vector_type(8)));
typedef float floatx4 __attribute__((ext_vector_type(4)));
typedef float floatx16 __attribute__((ext_vector_type(16)));

// -------- weight prep: fp32 [K,N] row-major -> fp16 MFMA-fragment order -----
// 32x32x16 layout (layers 0..4): kb=k>>4, half=(k>>3)&1, j=k&7, nt=n>>5,
//   lane=half*32+(n&31), dst=((kb*(N/32)+nt)*64+lane)*8+j.
// 16x16x32 layout (layer 5 = Wl4): kb=k>>5, quad=(k>>3)&3, j=k&7, nt=n>>4,
//   lane=quad*16+(n&15), dst=((kb*(N/16)+nt)*64+lane)*8+j.
struct PrepArgsV11 { const float* in[6]; };

__global__ __launch_bounds__(256) void v11_prep(PrepArgsV11 p, _Float16* Bf) {
  const int sz[6]  = {65536, 65536, 262144, 131072, 32768, 8192};
  const int lgN[6] = {8, 8, 9, 8, 7, 6};
  const int off[6] = {0, 65536, 131072, 393216, 524288, 557056};
  int e = blockIdx.x * 256 + threadIdx.x;
  for (int i = 0; i < 6; ++i) {
    if (e < sz[i]) {
      int N = 1 << lgN[i];
      int k = e >> lgN[i];
      int n = e & (N - 1);
      float w = p.in[i][e];
      int dst;
      if (i < 5) {
        int kb = k >> 4, half = (k >> 3) & 1, j = k & 7;
        int nt = n >> 5;
        int lane = half * 32 + (n & 31);
        dst = ((kb * (N >> 5) + nt) * 64 + lane) * 8 + j;
      } else {
        int kb = k >> 5, quad = (k >> 3) & 3, j = k & 7;
        int nt = n >> 4;
        int lane = quad * 16 + (n & 15);
        dst = ((kb * (N >> 4) + nt) * 64 + lane) * 8 + j;
      }
      Bf[off[i] + dst] = (_Float16)w;   // exact: weights are bf16-valued
      return;
    }
    e -= sz[i];
  }
}

// -------- 32x32x16 in-LDS layer with B register double-buffer ---------------
// MT m-tiles (32 rows), NT n-tiles (32 cols) per wave (4 waves => N=NT*128),
// KB k-steps of 16. ENC_IN: A stride 264 halves; else 520.
// OUT_MODE 0: relu->encode; 1: relu->head (encode rows r=2p+s); 2: relu->head.
template<int MT, int NT, int KB, bool ENC_IN, int OUT_MODE>
__device__ __forceinline__ void layer32(
    const _Float16* __restrict__ Bf, const float* __restrict__ bias,
    _Float16* sA, int wave, int lane) {
  const int n5 = lane & 31, khalf = lane >> 5;
  const int n0 = wave * (NT * 32);
  const int STRIDE = ENC_IN ? 264 : 520;
  const _Float16* bp = Bf + ((size_t)(wave * NT) * 64 + lane) * 8;

  floatx16 acc[MT][NT];
#pragma unroll
  for (int mt = 0; mt < MT; ++mt)
#pragma unroll
    for (int nt = 0; nt < NT; ++nt)
#pragma unroll
      for (int q = 0; q < 16; ++q) acc[mt][nt][q] = 0.f;

  half8 bbuf[2][NT];
#pragma unroll
  for (int nt = 0; nt < NT; ++nt)
    bbuf[0][nt] = *(const half8*)(bp + nt * 512);

#pragma unroll 2
  for (int kb = 0; kb < KB; ++kb) {
    const int cur = kb & 1, nxt = cur ^ 1;
    if (kb + 1 < KB) {
#pragma unroll
      for (int nt = 0; nt < NT; ++nt)
        bbuf[nxt][nt] = *(const half8*)(bp + (size_t)(kb + 1) * (NT * 2048) + nt * 512);
    }
    half8 av[MT];
#pragma unroll
    for (int mt = 0; mt < MT; ++mt)
      av[mt] = *(const half8*)(sA + (mt * 32 + n5) * STRIDE + kb * 16 + khalf * 8);
#pragma unroll
    for (int nt = 0; nt < NT; ++nt)
#pragma unroll
      for (int mt = 0; mt < MT; ++mt)
        acc[mt][nt] = __builtin_amdgcn_mfma_f32_32x32x16_f16(av[mt], bbuf[cur][nt], acc[mt][nt], 0, 0, 0);
  }

  __syncthreads();   // all waves done reading A; safe to overwrite in place

  // C/D: col = lane&31, row = (reg&3) + 8*(reg>>2) + 4*(lane>>5)  [m74/m101]
#pragma unroll
  for (int nt = 0; nt < NT; ++nt) {
    int c = n0 + nt * 32 + n5;
    float bv = bias[c];
#pragma unroll
    for (int mt = 0; mt < MT; ++mt) {
#pragma unroll
      for (int reg = 0; reg < 16; ++reg) {
        int r = mt * 32 + (reg & 3) + 8 * (reg >> 2) + 4 * khalf;
        float v = fmaxf(acc[mt][nt][reg] + bv, 0.f);
        int a;
        if (OUT_MODE == 0)      a = r * 264 + c;                        // encode
        else if (OUT_MODE == 1) a = (r >> 1) * 520 + (r & 1) * 256 + c; // concat
        else                    a = r * 520 + c;                        // head
        sA[a] = (_Float16)v;
      }
    }
  }
  __syncthreads();
}

// -------- 16x16x32 layer (H4 only): sigmoid -> global fp32 ------------------
template<int MT, int NT, int KB>
__device__ __forceinline__ void layer16_out(
    const _Float16* __restrict__ Bf, const float* __restrict__ bias,
    _Float16* sA, float* __restrict__ outg, int pair0, int wave, int lane) {
  const int quad = lane >> 4, lr = lane & 15;
  const int n0 = wave * (NT * 16);
  const _Float16* bp = Bf + ((size_t)(wave * NT) * 64 + lane) * 8;

  floatx4 acc[MT][NT];
#pragma unroll
  for (int mt = 0; mt < MT; ++mt)
#pragma unroll
    for (int nt = 0; nt < NT; ++nt)
      acc[mt][nt] = (floatx4){0.f, 0.f, 0.f, 0.f};

  half8 bbuf[2][NT];
#pragma unroll
  for (int nt = 0; nt < NT; ++nt)
    bbuf[0][nt] = *(const half8*)(bp + nt * 512);

#pragma unroll 2
  for (int kb = 0; kb < KB; ++kb) {
    const int cur = kb & 1, nxt = cur ^ 1;
    if (kb + 1 < KB) {
#pragma unroll
      for (int nt = 0; nt < NT; ++nt)
        bbuf[nxt][nt] = *(const half8*)(bp + (size_t)(kb + 1) * (NT * 2048) + nt * 512);
    }
    half8 av[MT];
#pragma unroll
    for (int mt = 0; mt < MT; ++mt)
      av[mt] = *(const half8*)(sA + (mt * 16 + lr) * 520 + kb * 32 + quad * 8);
#pragma unroll
    for (int nt = 0; nt < NT; ++nt)
#pragma unroll
      for (int mt = 0; mt < MT; ++mt)
        acc[mt][nt] = __builtin_amdgcn_mfma_f32_16x16x32_f16(av[mt], bbuf[cur][nt], acc[mt][nt], 0, 0, 0);
  }
  __syncthreads();

#pragma unroll
  for (int nt = 0; nt < NT; ++nt) {
    int c = n0 + nt * 16 + lr;
    float bv = bias[c];
#pragma unroll
    for (int mt = 0; mt < MT; ++mt) {
#pragma unroll
      for (int reg = 0; reg < 4; ++reg) {
        int r = mt * 16 + quad * 4 + reg;
        float v = acc[mt][nt][reg] + bv;
        int p = pair0 + r;
        if (p < 12500) outg[(size_t)p * 64 + c] = 1.0f / (1.0f + expf(-v));
      }
    }
  }
  __syncthreads();
}

// -------- megakernel: 32 pairs (64 side rows) per block ---------------------
__global__ __launch_bounds__(256, 3) void v11_mega(
    const float* __restrict__ x1, const float* __restrict__ x2,
    const float* __restrict__ W1, const float* __restrict__ b1,
    const _Float16* __restrict__ Bf,
    const float* __restrict__ b2, const float* __restrict__ b3,
    const float* __restrict__ bl1, const float* __restrict__ bl2,
    const float* __restrict__ bl3, const float* __restrict__ bl4,
    float* __restrict__ outg) {
  __shared__ _Float16 sA[16896];   // encode: [64][264]; head: [32][520]
  __shared__ float sM[64][3];

  int tid = threadIdx.x;
  int wave = tid >> 6, lane = tid & 63;
  int pair0 = blockIdx.x * 32;

  // Phase 0: per-side-row mean of the 4 node coords (64 rows)
  if (tid < 64) {
    int r = tid;
    int g = pair0 + (r >> 1);
    const float* xp = (r & 1) ? x2 : x1;
    float a0 = 0.f, a1 = 0.f, a2 = 0.f;
    if (g < 12500) {
      const float* q = xp + (size_t)g * 12;
      a0 = 0.25f * (q[0] + q[3] + q[6] + q[9]);
      a1 = 0.25f * (q[1] + q[4] + q[7] + q[10]);
      a2 = 0.25f * (q[2] + q[5] + q[8] + q[11]);
    }
    sM[r][0] = a0; sM[r][1] = a1; sM[r][2] = a2;
  }
  __syncthreads();

  // Phase 1: L1 (3 -> 256), fp32 VALU, fp16 into LDS (encode layout)
  {
    int c = tid;
    float w0 = W1[c], w1 = W1[256 + c], w2 = W1[512 + c], bb = b1[c];
#pragma unroll 4
    for (int r = 0; r < 64; ++r) {
      float v = fmaxf(sM[r][0] * w0 + sM[r][1] * w1 + sM[r][2] * w2 + bb, 0.f);
      sA[r * 264 + c] = (_Float16)v;
    }
  }
  __syncthreads();

  // L2: [64x256]@[256x256] relu, encode->encode
  layer32<2, 2, 16, true, 0>(Bf + 0,      b2,  sA, wave, lane);
  // L3: [64x256]@[256x256] relu, encode->head (concat)
  layer32<2, 2, 16, true, 1>(Bf + 65536,  b3,  sA, wave, lane);
  // H1: [32x512]@[512x512] relu
  layer32<1, 4, 32, false, 2>(Bf + 131072, bl1, sA, wave, lane);
  // H2: [32x512]@[512x256] relu
  layer32<1, 2, 32, false, 2>(Bf + 393216, bl2, sA, wave, lane);
  // H3: [32x256]@[256x128] relu
  layer32<1, 1, 16, false, 2>(Bf + 524288, bl3, sA, wave, lane);
  // H4: [32x128]@[128x64] sigmoid -> global (16x16 path)
  layer16_out<2, 1, 4>(Bf + 557056, bl4, sA, outg, pair0, wave, lane);
}

extern "C" void kernel_launch(void* const* d_in, const int* in_sizes, int n_in,
                              void* d_out, int out_size, void* d_ws, size_t ws_size,
                              hipStream_t stream) {
  const float* x1  = (const float*)d_in[0];
  const float* x2  = (const float*)d_in[3];
  const float* W1  = (const float*)d_in[6];
  const float* b1  = (const float*)d_in[7];
  const float* W2  = (const float*)d_in[8];
  const float* b2  = (const float*)d_in[9];
  const float* W3  = (const float*)d_in[10];
  const float* b3  = (const float*)d_in[11];
  const float* Wl1 = (const float*)d_in[12];
  const float* bl1 = (const float*)d_in[13];
  const float* Wl2 = (const float*)d_in[14];
  const float* bl2 = (const float*)d_in[15];
  const float* Wl3 = (const float*)d_in[16];
  const float* bl3 = (const float*)d_in[17];
  const float* Wl4 = (const float*)d_in[18];
  const float* bl4 = (const float*)d_in[19];

  _Float16* Bf = (_Float16*)d_ws;   // 565248 halves = 1.13 MB

  PrepArgsV11 pa;
  pa.in[0] = W2;  pa.in[1] = W3;  pa.in[2] = Wl1;
  pa.in[3] = Wl2; pa.in[4] = Wl3; pa.in[5] = Wl4;

  v11_prep<<<dim3(2208), dim3(256), 0, stream>>>(pa, Bf);
  v11_mega<<<dim3(391), dim3(256), 0, stream>>>(x1, x2, W1, b1, Bf,
                                                b2, b3, bl1, bl2, bl3, bl4,
                                                (float*)d_out);
}

// Round 12
// 122.270 us; speedup vs baseline: 1.0643x; 1.0643x over previous
//
#include <hip/hip_runtime.h>

// GraphPairClassifier v12: balanced megakernel — 250 blocks (1/CU) x 50 pairs
//   x 512 threads (8 waves). Each CU streams the 1.13 MB weight set exactly
//   once (R11 post-mortem: 391-block grid left ~135 CUs carrying 2 blocks =
//   2x B-stream; balance, not occupancy, was the lever). fp16 16x16x32 path
//   (best measured, R10). Distance-2 register prefetch of B (3-slot rolling).
//   Encode rows padded 100->112 (MT=7), head 50->64; sA pre-zeroed so pad
//   rows stay finite; H4 global writes guarded r<50.
// Dtypes: device inputs FP32 (bf16-quantized values => fp16 weights exact);
//   output FP32. absmax 3.9e-3 stable R6-R11.

typedef _Float16 half8 __attribute__((ext_vector_type(8)));
typedef float floatx4 __attribute__((ext_vector_type(4)));

// -------- weight prep: fp32 [K,N] row-major -> fp16 16x16x32-fragment order -
// dst for (k,n): kb=k>>5, quad=(k>>3)&3, j=k&7, nt=n>>4, lane=quad*16+(n&15),
//   dst = ((kb*(N/16)+nt)*64+lane)*8 + j.   (identical to v10)
struct PrepArgsV12 { const float* in[6]; };

__global__ __launch_bounds__(256) void v12_prep(PrepArgsV12 p, _Float16* Bf) {
  const int sz[6]  = {65536, 65536, 262144, 131072, 32768, 8192};
  const int lgN[6] = {8, 8, 9, 8, 7, 6};
  const int off[6] = {0, 65536, 131072, 393216, 524288, 557056};
  int e = blockIdx.x * 256 + threadIdx.x;
  for (int i = 0; i < 6; ++i) {
    if (e < sz[i]) {
      int N = 1 << lgN[i];
      int k = e >> lgN[i];
      int n = e & (N - 1);
      float w = p.in[i][e];
      int kb = k >> 5, quad = (k >> 3) & 3, j = k & 7;
      int nt = n >> 4;
      int lane = quad * 16 + (n & 15);
      int dst = ((kb * (N >> 4) + nt) * 64 + lane) * 8 + j;
      Bf[off[i] + dst] = (_Float16)w;   // exact: weights are bf16-valued
      return;
    }
    e -= sz[i];
  }
}

// -------- generic in-LDS layer, distance-2 B prefetch -----------------------
// MT m-tiles (16 rows from m0), NT n-tiles per wave-slot nw, TNT = N/16 total
// n-tiles, KB k-steps of 32. ENC_IN: A stride 264 halves; else 520.
// OUT_MODE 0: relu->encode; 1: relu->head (encode rows r=2p+s -> pair rows);
//          2: relu->head; 3: sigmoid->global fp32 (rows r<50 only).
template<int MT, int NT, int TNT, int KB, bool ENC_IN, int OUT_MODE>
__device__ __forceinline__ void layer(
    const _Float16* __restrict__ Bf, const float* __restrict__ bias,
    _Float16* sA, float* __restrict__ outg, int pair0, int nw, int m0, int lane) {
  const int quad = lane >> 4, lr = lane & 15;
  const int n0 = nw * (NT * 16);
  const int STRIDE = ENC_IN ? 264 : 520;
  const _Float16* bp = Bf + ((size_t)(nw * NT) * 64 + lane) * 8;

  floatx4 acc[MT][NT];
#pragma unroll
  for (int mt = 0; mt < MT; ++mt)
#pragma unroll
    for (int nt = 0; nt < NT; ++nt)
      acc[mt][nt] = (floatx4){0.f, 0.f, 0.f, 0.f};

  half8 bbuf[3][NT];
#pragma unroll
  for (int nt = 0; nt < NT; ++nt) {
    bbuf[0][nt] = *(const half8*)(bp + nt * 512);
    bbuf[1][nt] = *(const half8*)(bp + (size_t)TNT * 512 + nt * 512);
  }

#pragma unroll
  for (int kb = 0; kb < KB; ++kb) {
    const int cur = kb % 3;
    half8 av[MT];
#pragma unroll
    for (int mt = 0; mt < MT; ++mt)
      av[mt] = *(const half8*)(sA + (m0 + mt * 16 + lr) * STRIDE + kb * 32 + quad * 8);
#pragma unroll
    for (int nt = 0; nt < NT; ++nt)
#pragma unroll
      for (int mt = 0; mt < MT; ++mt)
        acc[mt][nt] = __builtin_amdgcn_mfma_f32_16x16x32_f16(av[mt], bbuf[cur][nt], acc[mt][nt], 0, 0, 0);
    if (kb + 2 < KB) {
      const int nxt = (kb + 2) % 3;
#pragma unroll
      for (int nt = 0; nt < NT; ++nt)
        bbuf[nxt][nt] = *(const half8*)(bp + (size_t)(kb + 2) * (TNT * 512) + nt * 512);
    }
  }

  __syncthreads();   // all waves done reading A; safe to overwrite in place

#pragma unroll
  for (int nt = 0; nt < NT; ++nt) {
    int c = n0 + nt * 16 + lr;
    float bv = bias[c];
#pragma unroll
    for (int mt = 0; mt < MT; ++mt) {
#pragma unroll
      for (int reg = 0; reg < 4; ++reg) {
        int r = m0 + mt * 16 + quad * 4 + reg;
        float v = acc[mt][nt][reg] + bv;
        if (OUT_MODE <= 2) {
          v = fmaxf(v, 0.f);
          int a;
          if (OUT_MODE == 0)      a = r * 264 + c;                        // encode
          else if (OUT_MODE == 1) a = (r >> 1) * 520 + (r & 1) * 256 + c; // concat
          else                    a = r * 520 + c;                        // head
          sA[a] = (_Float16)v;
        } else {
          if (r < 50) outg[(size_t)(pair0 + r) * 64 + c] = 1.0f / (1.0f + expf(-v));
        }
      }
    }
  }
  __syncthreads();
}

// -------- megakernel: 50 pairs (100 side rows, padded 112) per block --------
__global__ __launch_bounds__(512, 2) void v12_mega(
    const float* __restrict__ x1, const float* __restrict__ x2,
    const float* __restrict__ W1, const float* __restrict__ b1,
    const _Float16* __restrict__ Bf,
    const float* __restrict__ b2, const float* __restrict__ b3,
    const float* __restrict__ bl1, const float* __restrict__ bl2,
    const float* __restrict__ bl3, const float* __restrict__ bl4,
    float* __restrict__ outg) {
  __shared__ _Float16 sA[33280];   // encode: [112][264]=29568; head: [64][520]=33280
  __shared__ float sM[112][3];

  int tid = threadIdx.x;
  int wave = tid >> 6, lane = tid & 63;
  int pair0 = blockIdx.x * 50;

  // Phase -1: zero sA so pad rows stay finite (no fp16 NaN bit patterns)
  for (int i = tid; i < 16640; i += 512) ((float*)sA)[i] = 0.f;

  // Phase 0: per-side-row mean of the 4 node coords (100 real rows, 12 pad)
  if (tid < 112) {
    int r = tid;
    float a0 = 0.f, a1 = 0.f, a2 = 0.f;
    if (r < 100) {
      int g = pair0 + (r >> 1);                    // always < 12500
      const float* q = ((r & 1) ? x2 : x1) + (size_t)g * 12;
      a0 = 0.25f * (q[0] + q[3] + q[6] + q[9]);
      a1 = 0.25f * (q[1] + q[4] + q[7] + q[10]);
      a2 = 0.25f * (q[2] + q[5] + q[8] + q[11]);
    }
    sM[r][0] = a0; sM[r][1] = a1; sM[r][2] = a2;
  }
  __syncthreads();

  // Phase 1: L1 (3 -> 256), fp32 VALU, fp16 into LDS (encode layout, 112 rows)
  {
    int c = tid & 255;
    float w0 = W1[c], w1 = W1[256 + c], w2 = W1[512 + c], bb = b1[c];
    for (int r = (tid >> 8); r < 112; r += 2) {
      float v = fmaxf(sM[r][0] * w0 + sM[r][1] * w1 + sM[r][2] * w2 + bb, 0.f);
      sA[r * 264 + c] = (_Float16)v;
    }
  }
  __syncthreads();

  // L2: [112x256]@[256x256] relu, encode->encode
  layer<7, 2, 16,  8, true,  0>(Bf + 0,      b2,  sA, nullptr, pair0, wave, 0, lane);
  // L3: [112x256]@[256x256] relu, encode->head (concat)
  layer<7, 2, 16,  8, true,  1>(Bf + 65536,  b3,  sA, nullptr, pair0, wave, 0, lane);
  // H1: [64x512]@[512x512] relu
  layer<4, 4, 32, 16, false, 2>(Bf + 131072, bl1, sA, nullptr, pair0, wave, 0, lane);
  // H2: [64x512]@[512x256] relu
  layer<4, 2, 16, 16, false, 2>(Bf + 393216, bl2, sA, nullptr, pair0, wave, 0, lane);
  // H3: [64x256]@[256x128] relu
  layer<4, 1,  8,  8, false, 2>(Bf + 524288, bl3, sA, nullptr, pair0, wave, 0, lane);
  // H4: [64x128]@[128x64] sigmoid -> global; waves split 4 n-chunks x 2 m-halves
  layer<2, 1,  4,  4, false, 3>(Bf + 557056, bl4, sA, outg,    pair0,
                                wave & 3, (wave >> 2) * 32, lane);
}

extern "C" void kernel_launch(void* const* d_in, const int* in_sizes, int n_in,
                              void* d_out, int out_size, void* d_ws, size_t ws_size,
                              hipStream_t stream) {
  const float* x1  = (const float*)d_in[0];
  const float* x2  = (const float*)d_in[3];
  const float* W1  = (const float*)d_in[6];
  const float* b1  = (const float*)d_in[7];
  const float* W2  = (const float*)d_in[8];
  const float* b2  = (const float*)d_in[9];
  const float* W3  = (const float*)d_in[10];
  const float* b3  = (const float*)d_in[11];
  const float* Wl1 = (const float*)d_in[12];
  const float* bl1 = (const float*)d_in[13];
  const float* Wl2 = (const float*)d_in[14];
  const float* bl2 = (const float*)d_in[15];
  const float* Wl3 = (const float*)d_in[16];
  const float* bl3 = (const float*)d_in[17];
  const float* Wl4 = (const float*)d_in[18];
  const float* bl4 = (const float*)d_in[19];

  _Float16* Bf = (_Float16*)d_ws;   // 565248 halves = 1.13 MB

  PrepArgsV12 pa;
  pa.in[0] = W2;  pa.in[1] = W3;  pa.in[2] = Wl1;
  pa.in[3] = Wl2; pa.in[4] = Wl3; pa.in[5] = Wl4;

  v12_prep<<<dim3(2208), dim3(256), 0, stream>>>(pa, Bf);
  v12_mega<<<dim3(250), dim3(512), 0, stream>>>(x1, x2, W1, b1, Bf,
                                                b2, b3, bl1, bl2, bl3, bl4,
                                                (float*)d_out);
}

// Round 13
// 121.280 us; speedup vs baseline: 1.0730x; 1.0082x over previous
//
#include <hip/hip_runtime.h>

// GraphPairClassifier v13: balanced megakernel — 250 blocks x 50 pairs x
//   1024 threads (16 waves = 4 waves/SIMD; R12 post-mortem: mega was L2-
//   latency-exposed at 2 waves/SIMD). Each CU streams the 1.13 MB weight set
//   once; fp16 16x16x32 MFMA; distance-2 register B-prefetch (3-slot).
//   Encode rows 100->112 pad, head 50->64 pad; sA pre-zeroed; H4 guarded.
// Dtypes: device inputs FP32 (bf16-quantized values => fp16 weights exact);
//   output FP32. absmax 3.9e-3 stable R6-R12.

typedef _Float16 half8 __attribute__((ext_vector_type(8)));
typedef float floatx4 __attribute__((ext_vector_type(4)));

// -------- weight prep: fp32 [K,N] row-major -> fp16 16x16x32-fragment order -
// fragment f: lane=f&63, rem=f>>6, nt=rem%(N/16), kb=rem/(N/16);
//   n = nt*16+(lane&15), k = kb*32+(lane>>4)*8+j, j=0..7.
// One thread per fragment: 8 strided reads, one contiguous 16B write.
struct PrepArgsV13 { const float* in[6]; };

__global__ __launch_bounds__(256) void v13_prep(PrepArgsV13 p, _Float16* Bf) {
  const int frags[6] = {8192, 8192, 32768, 16384, 4096, 1024};  // sz/8
  const int lgN[6]   = {8, 8, 9, 8, 7, 6};
  const int off[6]   = {0, 65536, 131072, 393216, 524288, 557056};
  int f = blockIdx.x * 256 + threadIdx.x;
  for (int i = 0; i < 6; ++i) {
    if (f < frags[i]) {
      int N = 1 << lgN[i];
      int lane = f & 63, rem = f >> 6;
      int nt = rem & ((N >> 4) - 1);
      int kb = rem >> (lgN[i] - 4);
      int n = nt * 16 + (lane & 15);
      int k0 = kb * 32 + (lane >> 4) * 8;
      const float* src = p.in[i] + (size_t)k0 * N + n;
      half8 v;
#pragma unroll
      for (int j = 0; j < 8; ++j) v[j] = (_Float16)src[(size_t)j * N];
      *(half8*)(Bf + off[i] + (size_t)f * 8) = v;   // exact: bf16-valued
      return;
    }
    f -= frags[i];
  }
}

// -------- generic in-LDS layer, distance-2 B prefetch -----------------------
// MT m-tiles (16 rows from m0), NT n-tiles at n-slot nw, TNT = N/16 total
// n-tiles, KB k-steps of 32. ENC_IN: A stride 264 halves; else 520.
// OUT_MODE 0: relu->encode; 1: relu->head (encode rows r=2p+s -> pair rows);
//          2: relu->head; 3: sigmoid->global fp32 (rows r<50 only).
template<int MT, int NT, int TNT, int KB, bool ENC_IN, int OUT_MODE>
__device__ __forceinline__ void layer(
    const _Float16* __restrict__ Bf, const float* __restrict__ bias,
    _Float16* sA, float* __restrict__ outg, int pair0, int nw, int m0, int lane) {
  const int quad = lane >> 4, lr = lane & 15;
  const int n0 = nw * (NT * 16);
  const int STRIDE = ENC_IN ? 264 : 520;
  const _Float16* bp = Bf + ((size_t)(nw * NT) * 64 + lane) * 8;

  floatx4 acc[MT][NT];
#pragma unroll
  for (int mt = 0; mt < MT; ++mt)
#pragma unroll
    for (int nt = 0; nt < NT; ++nt)
      acc[mt][nt] = (floatx4){0.f, 0.f, 0.f, 0.f};

  half8 bbuf[3][NT];
#pragma unroll
  for (int nt = 0; nt < NT; ++nt) {
    bbuf[0][nt] = *(const half8*)(bp + nt * 512);
    bbuf[1][nt] = *(const half8*)(bp + (size_t)TNT * 512 + nt * 512);
  }

#pragma unroll
  for (int kb = 0; kb < KB; ++kb) {
    const int cur = kb % 3;
    half8 av[MT];
#pragma unroll
    for (int mt = 0; mt < MT; ++mt)
      av[mt] = *(const half8*)(sA + (m0 + mt * 16 + lr) * STRIDE + kb * 32 + quad * 8);
#pragma unroll
    for (int nt = 0; nt < NT; ++nt)
#pragma unroll
      for (int mt = 0; mt < MT; ++mt)
        acc[mt][nt] = __builtin_amdgcn_mfma_f32_16x16x32_f16(av[mt], bbuf[cur][nt], acc[mt][nt], 0, 0, 0);
    if (kb + 2 < KB) {
      const int nxt = (kb + 2) % 3;
#pragma unroll
      for (int nt = 0; nt < NT; ++nt)
        bbuf[nxt][nt] = *(const half8*)(bp + (size_t)(kb + 2) * (TNT * 512) + nt * 512);
    }
  }

  __syncthreads();   // all waves done reading A; safe to overwrite in place

#pragma unroll
  for (int nt = 0; nt < NT; ++nt) {
    int c = n0 + nt * 16 + lr;
    float bv = bias[c];
#pragma unroll
    for (int mt = 0; mt < MT; ++mt) {
#pragma unroll
      for (int reg = 0; reg < 4; ++reg) {
        int r = m0 + mt * 16 + quad * 4 + reg;
        float v = acc[mt][nt][reg] + bv;
        if (OUT_MODE <= 2) {
          v = fmaxf(v, 0.f);
          int a;
          if (OUT_MODE == 0)      a = r * 264 + c;                        // encode
          else if (OUT_MODE == 1) a = (r >> 1) * 520 + (r & 1) * 256 + c; // concat
          else                    a = r * 520 + c;                        // head
          sA[a] = (_Float16)v;
        } else {
          if (r < 50) outg[(size_t)(pair0 + r) * 64 + c] = 1.0f / (1.0f + expf(-v));
        }
      }
    }
  }
  __syncthreads();
}

// -------- megakernel: 50 pairs (100 side rows, pad 112) per 1024-thr block --
__global__ __launch_bounds__(1024) void v13_mega(
    const float* __restrict__ x1, const float* __restrict__ x2,
    const float* __restrict__ W1, const float* __restrict__ b1,
    const _Float16* __restrict__ Bf,
    const float* __restrict__ b2, const float* __restrict__ b3,
    const float* __restrict__ bl1, const float* __restrict__ bl2,
    const float* __restrict__ bl3, const float* __restrict__ bl4,
    float* __restrict__ outg) {
  __shared__ _Float16 sA[33280];   // encode: [112][264]=29568; head: [64][520]=33280
  __shared__ float sM[112][3];

  int tid = threadIdx.x;
  int wave = tid >> 6, lane = tid & 63;
  int pair0 = blockIdx.x * 50;

  // Phase -1: zero sA so pad rows stay finite
  for (int i = tid; i < 16640; i += 1024) ((float*)sA)[i] = 0.f;

  // Phase 0: per-side-row mean of the 4 node coords (100 real rows, 12 pad)
  if (tid < 112) {
    int r = tid;
    float a0 = 0.f, a1 = 0.f, a2 = 0.f;
    if (r < 100) {
      int g = pair0 + (r >> 1);                    // always < 12500
      const float* q = ((r & 1) ? x2 : x1) + (size_t)g * 12;
      a0 = 0.25f * (q[0] + q[3] + q[6] + q[9]);
      a1 = 0.25f * (q[1] + q[4] + q[7] + q[10]);
      a2 = 0.25f * (q[2] + q[5] + q[8] + q[11]);
    }
    sM[r][0] = a0; sM[r][1] = a1; sM[r][2] = a2;
  }
  __syncthreads();

  // Phase 1: L1 (3 -> 256), fp32 VALU, fp16 into LDS (encode layout, 112 rows)
  {
    int c = tid & 255;
    float w0 = W1[c], w1 = W1[256 + c], w2 = W1[512 + c], bb = b1[c];
    for (int r = (tid >> 8); r < 112; r += 4) {
      float v = fmaxf(sM[r][0] * w0 + sM[r][1] * w1 + sM[r][2] * w2 + bb, 0.f);
      sA[r * 264 + c] = (_Float16)v;
    }
  }
  __syncthreads();

  // L2: [112x256]@[256x256] relu, encode->encode   (16 n-slots x NT=1)
  layer<7, 1, 16,  8, true,  0>(Bf + 0,      b2,  sA, nullptr, pair0, wave, 0, lane);
  // L3: [112x256]@[256x256] relu, encode->head (concat)
  layer<7, 1, 16,  8, true,  1>(Bf + 65536,  b3,  sA, nullptr, pair0, wave, 0, lane);
  // H1: [64x512]@[512x512] relu                    (16 n-slots x NT=2)
  layer<4, 2, 32, 16, false, 2>(Bf + 131072, bl1, sA, nullptr, pair0, wave, 0, lane);
  // H2: [64x512]@[512x256] relu                    (16 n-slots x NT=1)
  layer<4, 1, 16, 16, false, 2>(Bf + 393216, bl2, sA, nullptr, pair0, wave, 0, lane);
  // H3: [64x256]@[256x128] relu                    (8 n-slots x 2 m-groups)
  layer<2, 1,  8,  8, false, 2>(Bf + 524288, bl3, sA, nullptr, pair0,
                                wave & 7, (wave >> 3) * 32, lane);
  // H4: [64x128]@[128x64] sigmoid -> global        (4 n-slots x 4 m-groups)
  layer<1, 1,  4,  4, false, 3>(Bf + 557056, bl4, sA, outg,    pair0,
                                wave & 3, (wave >> 2) * 16, lane);
}

extern "C" void kernel_launch(void* const* d_in, const int* in_sizes, int n_in,
                              void* d_out, int out_size, void* d_ws, size_t ws_size,
                              hipStream_t stream) {
  const float* x1  = (const float*)d_in[0];
  const float* x2  = (const float*)d_in[3];
  const float* W1  = (const float*)d_in[6];
  const float* b1  = (const float*)d_in[7];
  const float* W2  = (const float*)d_in[8];
  const float* b2  = (const float*)d_in[9];
  const float* W3  = (const float*)d_in[10];
  const float* b3  = (const float*)d_in[11];
  const float* Wl1 = (const float*)d_in[12];
  const float* bl1 = (const float*)d_in[13];
  const float* Wl2 = (const float*)d_in[14];
  const float* bl2 = (const float*)d_in[15];
  const float* Wl3 = (const float*)d_in[16];
  const float* bl3 = (const float*)d_in[17];
  const float* Wl4 = (const float*)d_in[18];
  const float* bl4 = (const float*)d_in[19];

  _Float16* Bf = (_Float16*)d_ws;   // 565248 halves = 1.13 MB

  PrepArgsV13 pa;
  pa.in[0] = W2;  pa.in[1] = W3;  pa.in[2] = Wl1;
  pa.in[3] = Wl2; pa.in[4] = Wl3; pa.in[5] = Wl4;

  v13_prep<<<dim3(276), dim3(256), 0, stream>>>(pa, Bf);
  v13_mega<<<dim3(250), dim3(1024), 0, stream>>>(x1, x2, W1, b1, Bf,
                                                 b2, b3, bl1, bl2, bl3, bl4,
                                                 (float*)d_out);
}